// Round 14
// baseline (345.490 us; speedup 1.0000x reference)
//
#include <hip/hip_runtime.h>

#define N_NODES 50000
#define E_EDGES 1600000
#define FN 8
#define FE 8
#define HID 16
#define IH 10
#define NB_SCAN 196   // ceil(50000/256)

// ---------------- workspace layout ----------------
#define I_OFF   50048
#define I_RANK  100096
#define I_BSUM  1700096
#define I_BBASE 1700352
#define I_TOTAL 1700608
#define F_H     0
#define F_H2    800000
#define F_MSG   1300000
#define F_TOTAL 26900000
#define WS_NEED ((size_t)I_TOTAL*4 + (size_t)F_TOTAL*4)

typedef __attribute__((ext_vector_type(4))) unsigned uint4v;

// ================= CSR build (padded counters: one per 64B line) =================
__global__ __launch_bounds__(256) void count_rank_k(
    const int* __restrict__ ei, int* __restrict__ cntP, int* __restrict__ rank)
{
    int e = blockIdx.x * 256 + threadIdx.x;
    if (e >= E_EDGES) return;
    int dst = ei[E_EDGES + e];
    rank[e] = atomicAdd(&cntP[dst * 16], 1);
}

__global__ __launch_bounds__(256) void blocksum_k(
    const int* __restrict__ cntP, int* __restrict__ bsum)
{
    __shared__ int sh[256];
    int t = threadIdx.x;
    int idx = blockIdx.x * 256 + t;
    sh[t] = (idx < N_NODES) ? cntP[idx * 16] : 0;
    __syncthreads();
#pragma unroll
    for (int d = 128; d > 0; d >>= 1) {
        if (t < d) sh[t] += sh[t + d];
        __syncthreads();
    }
    if (t == 0) bsum[blockIdx.x] = sh[0];
}

__global__ __launch_bounds__(256) void scan_bsums_k(
    const int* __restrict__ bsum, int* __restrict__ bbase)
{
    __shared__ int sh[256];
    int t = threadIdx.x;
    int v = (t < NB_SCAN) ? bsum[t] : 0;
    sh[t] = v;
    __syncthreads();
#pragma unroll
    for (int d = 1; d < 256; d <<= 1) {
        int u = (t >= d) ? sh[t - d] : 0;
        __syncthreads();
        sh[t] += u;
        __syncthreads();
    }
    if (t < NB_SCAN) bbase[t] = sh[t] - v;
}

__global__ __launch_bounds__(256) void offsets_k(
    const int* __restrict__ cntP, const int* __restrict__ bbase,
    int* __restrict__ offset)
{
    __shared__ int sh[256];
    int t = threadIdx.x;
    int b = blockIdx.x;
    int idx = b * 256 + t;
    int v = (idx < N_NODES) ? cntP[idx * 16] : 0;
    sh[t] = v;
    __syncthreads();
#pragma unroll
    for (int d = 1; d < 256; d <<= 1) {
        int u = (t >= d) ? sh[t - d] : 0;
        __syncthreads();
        sh[t] += u;
        __syncthreads();
    }
    int incl = sh[t];
    int base = bbase[b];
    if (idx < N_NODES) offset[idx] = base + incl - v;
    if (idx == N_NODES - 1) offset[N_NODES] = base + incl;
}

// ================= helpers =================
__device__ __forceinline__ void load8(const float* __restrict__ p, float v[8]) {
    const float4* q = reinterpret_cast<const float4*>(p);
    float4 a = q[0], b = q[1];
    v[0]=a.x; v[1]=a.y; v[2]=a.z; v[3]=a.w;
    v[4]=b.x; v[5]=b.y; v[6]=b.z; v[7]=b.w;
}

__device__ __forceinline__ void edge_mlp_seq(
    const float eav[FE], const float* __restrict__ w1,
    const float* __restrict__ b1, float u[IH])
{
#pragma unroll
    for (int h = 0; h < IH; ++h) u[h] = b1[h];
#pragma unroll
    for (int k = 0; k < FE; ++k) {
        float ek = eav[k];
#pragma unroll
        for (int h = 0; h < IH; ++h) u[h] = fmaf(ek, w1[k*IH + h], u[h]);
    }
#pragma unroll
    for (int h = 0; h < IH; ++h) u[h] = fmaxf(u[h], 0.f);
}

// round-to-nearest bf16x2 pack (bit trick, ~5 VALU)
__device__ __forceinline__ unsigned pk2(float a, float b) {
    unsigned au = __float_as_uint(a) + 0x8000u;
    unsigned bu = __float_as_uint(b) + 0x8000u;
    return (au >> 16) | (bu & 0xFFFF0000u);
}
__device__ __forceinline__ float upbf(unsigned short us) {
    return __uint_as_float(((unsigned)us) << 16);
}

// ================= conv0: 1 edge/thread, LDS transpose + bf16 NT scatter =======
__global__ __launch_bounds__(256) void conv0_scatter_k(
    const float* __restrict__ x, const float* __restrict__ ea,
    const int* __restrict__ ei,
    const float* __restrict__ w1, const float* __restrict__ b1,
    const float* __restrict__ w2, const float* __restrict__ b2,
    const int* __restrict__ offset, const int* __restrict__ rank,
    unsigned* __restrict__ msgu)         // bf16 msgbuf viewed as u32; row = pos*8
{
    __shared__ float smsg[256 * 17];
    __shared__ int   plds[256];

    int t = threadIdx.x;
    int e = blockIdx.x * 256 + t;        // grid exact: E/256
    int src = ei[e];
    int dst = ei[E_EDGES + e];
    plds[t] = offset[dst] + rank[e];

    float eav[FE];
    load8(ea + (size_t)e * FE, eav);
    float u[IH];
    edge_mlp_seq(eav, w1, b1, u);
    float xv[FN];
    load8(x + (size_t)src * FN, xv);

    float msg[HID];
#pragma unroll
    for (int o = 0; o < HID; ++o) msg[o] = 0.f;
#pragma unroll
    for (int i = 0; i < FN; ++i) {
        float xi = xv[i];
#pragma unroll
        for (int o = 0; o < HID; ++o)
            msg[o] = fmaf(xi, b2[i*HID + o], msg[o]);
    }
#pragma unroll
    for (int h = 0; h < IH; ++h) {
        float tt[HID];
#pragma unroll
        for (int o = 0; o < HID; ++o) tt[o] = 0.f;
        const float* wp = w2 + h * (FN*HID);
#pragma unroll
        for (int i = 0; i < FN; ++i) {
            float xi = xv[i];
#pragma unroll
            for (int o = 0; o < HID; ++o)
                tt[o] = fmaf(xi, wp[i*HID + o], tt[o]);
        }
        float uh = u[h];
#pragma unroll
        for (int o = 0; o < HID; ++o) msg[o] = fmaf(uh, tt[o], msg[o]);
    }

#pragma unroll
    for (int o = 0; o < HID; ++o) smsg[t*17 + o] = msg[o];
    __syncthreads();

    int q   = t & 1;        // 16B half of the 32B row
    int eb0 = t >> 1;       // 0..127
#pragma unroll
    for (int rep = 0; rep < 2; ++rep) {
        int eL  = eb0 + rep * 128;
        int pos = plds[eL];
        const float* s = &smsg[eL*17 + q*8];
        uint4v v;
        v.x = pk2(s[0], s[1]); v.y = pk2(s[2], s[3]);
        v.z = pk2(s[4], s[5]); v.w = pk2(s[6], s[7]);
        __builtin_nontemporal_store(
            v, reinterpret_cast<uint4v*>(msgu + (size_t)pos * 8 + q * 4));
    }
}

// ================= node0: bf16 segmented reduce (NT loads) + root + relu ========
__global__ __launch_bounds__(256) void node0_red_k(
    const float* __restrict__ x, const unsigned short* __restrict__ msg16,
    const int* __restrict__ offset,
    const float* __restrict__ root, const float* __restrict__ bias,
    float* __restrict__ h)
{
    int idx = blockIdx.x * 256 + threadIdx.x;
    if (idx >= N_NODES * HID) return;
    int n = idx >> 4;
    int o = idx & 15;
    int beg = offset[n], end = offset[n + 1];
    float s = bias[o];
    for (int j = beg; j < end; ++j)
        s += upbf(__builtin_nontemporal_load(&msg16[(size_t)j * 16 + o]));
    const float* xr = x + (size_t)n * FN;
#pragma unroll
    for (int i = 0; i < FN; ++i) s = fmaf(xr[i], root[i*HID + o], s);
    h[idx] = fmaxf(s, 0.f);
}

// ================= conv1: 1 edge/thread, LDS transpose + bf16 NT scatter =======
__global__ __launch_bounds__(256) void conv1_scatter_k(
    const float* __restrict__ hin, const float* __restrict__ ea,
    const int* __restrict__ ei,
    const float* __restrict__ w1, const float* __restrict__ b1,
    const float* __restrict__ w2, const float* __restrict__ b2,
    const int* __restrict__ offset, const int* __restrict__ rank,
    unsigned* __restrict__ msgu)         // bf16 rows, 16 slots (10 used)
{
    __shared__ float smsg[256 * 17];
    __shared__ int   plds[256];

    int t = threadIdx.x;
    int e = blockIdx.x * 256 + t;
    int src = ei[e];
    int dst = ei[E_EDGES + e];
    plds[t] = offset[dst] + rank[e];

    float eav[FE];
    load8(ea + (size_t)e * FE, eav);
    float u[IH];
    edge_mlp_seq(eav, w1, b1, u);
    float hv[HID];
    load8(hin + (size_t)src * HID,     hv);
    load8(hin + (size_t)src * HID + 8, hv + 8);

    float msg[HID];
#pragma unroll
    for (int o = 0; o < HID; ++o) msg[o] = 0.f;
#pragma unroll
    for (int i = 0; i < HID; ++i) {
        float hi = hv[i];
#pragma unroll
        for (int o = 0; o < IH; ++o)
            msg[o] = fmaf(hi, b2[i*IH + o], msg[o]);
    }
#pragma unroll
    for (int hh = 0; hh < IH; ++hh) {
        float tt[IH];
#pragma unroll
        for (int o = 0; o < IH; ++o) tt[o] = 0.f;
        const float* wp = w2 + hh * (HID*IH);
#pragma unroll
        for (int i = 0; i < HID; ++i) {
            float hi = hv[i];
#pragma unroll
            for (int o = 0; o < IH; ++o)
                tt[o] = fmaf(hi, wp[i*IH + o], tt[o]);
        }
        float uh = u[hh];
#pragma unroll
        for (int o = 0; o < IH; ++o) msg[o] = fmaf(uh, tt[o], msg[o]);
    }

#pragma unroll
    for (int o = 0; o < HID; ++o) smsg[t*17 + o] = msg[o];   // 10..15 zeros
    __syncthreads();

    int q   = t & 1;
    int eb0 = t >> 1;
#pragma unroll
    for (int rep = 0; rep < 2; ++rep) {
        int eL  = eb0 + rep * 128;
        int pos = plds[eL];
        const float* s = &smsg[eL*17 + q*8];
        uint4v v;
        v.x = pk2(s[0], s[1]); v.y = pk2(s[2], s[3]);
        v.z = pk2(s[4], s[5]); v.w = pk2(s[6], s[7]);
        __builtin_nontemporal_store(
            v, reinterpret_cast<uint4v*>(msgu + (size_t)pos * 8 + q * 4));
    }
}

// ================= node1: bf16 segmented reduce (NT loads) + root + relu ========
__global__ __launch_bounds__(256) void node1_red_k(
    const float* __restrict__ hin, const unsigned short* __restrict__ msg16,
    const int* __restrict__ offset,
    const float* __restrict__ root, const float* __restrict__ bias,
    float* __restrict__ h2)
{
    int idx = blockIdx.x * 256 + threadIdx.x;
    if (idx >= N_NODES * IH) return;
    int n = idx / IH;
    int o = idx - n * IH;
    int beg = offset[n], end = offset[n + 1];
    float s = bias[o];
    for (int j = beg; j < end; ++j)
        s += upbf(__builtin_nontemporal_load(&msg16[(size_t)j * 16 + o]));
    const float* hr = hin + (size_t)n * HID;
#pragma unroll
    for (int i = 0; i < HID; ++i) s = fmaf(hr[i], root[i*IH + o], s);
    h2[idx] = fmaxf(s, 0.f);
}

// ================= edge predictor =================
__global__ __launch_bounds__(256) void edge_pred_k(
    const float* __restrict__ h2, const float* __restrict__ ea,
    const int* __restrict__ ei,
    const float* __restrict__ w1, const float* __restrict__ b1,
    const float* __restrict__ w2, const float* __restrict__ b2,
    float* __restrict__ out)
{
    int e = blockIdx.x * 256 + threadIdx.x;
    if (e >= E_EDGES) return;
    int src = ei[e];
    float eav[FE];
    load8(ea + (size_t)e * FE, eav);
    float hv[IH];
    {
        const float2* p = reinterpret_cast<const float2*>(h2 + (size_t)src * IH);
        float2 a = p[0], b = p[1], c = p[2], d = p[3], f = p[4];
        hv[0]=a.x; hv[1]=a.y; hv[2]=b.x; hv[3]=b.y; hv[4]=c.x;
        hv[5]=c.y; hv[6]=d.x; hv[7]=d.y; hv[8]=f.x; hv[9]=f.y;
    }
    float t[IH];
#pragma unroll
    for (int j = 0; j < IH; ++j) t[j] = b1[j];
#pragma unroll
    for (int k = 0; k < FE; ++k) {
        float ek = eav[k];
#pragma unroll
        for (int j = 0; j < IH; ++j) t[j] = fmaf(ek, w1[k*IH + j], t[j]);
    }
#pragma unroll
    for (int k = 0; k < IH; ++k) {
        float hk = hv[k];
#pragma unroll
        for (int j = 0; j < IH; ++j) t[j] = fmaf(hk, w1[(FE + k)*IH + j], t[j]);
    }
    float score = b2[0];
#pragma unroll
    for (int j = 0; j < IH; ++j)
        score = fmaf(fmaxf(t[j], 0.f), w2[j], score);
    out[e] = score;
}

// ================= fallback (atomic) path =================
__global__ __launch_bounds__(256) void conv0_edge_k(
    const float* __restrict__ x, const float* __restrict__ ea,
    const int* __restrict__ ei,
    const float* __restrict__ w1, const float* __restrict__ b1,
    const float* __restrict__ w2, const float* __restrict__ b2,
    float* __restrict__ agg)
{
    int e = blockIdx.x * 256 + threadIdx.x;
    if (e >= E_EDGES) return;
    int src = ei[e];
    int dst = ei[E_EDGES + e];
    float eav[FE];
    load8(ea + (size_t)e * FE, eav);
    float u[IH];
    edge_mlp_seq(eav, w1, b1, u);
    float xv[FN];
    load8(x + (size_t)src * FN, xv);
    float msg[HID];
#pragma unroll
    for (int o = 0; o < HID; ++o) msg[o] = 0.f;
#pragma unroll
    for (int i = 0; i < FN; ++i) {
        float xi = xv[i];
#pragma unroll
        for (int o = 0; o < HID; ++o)
            msg[o] = fmaf(xi, b2[i*HID + o], msg[o]);
    }
#pragma unroll
    for (int h = 0; h < IH; ++h) {
        float t[HID];
#pragma unroll
        for (int o = 0; o < HID; ++o) t[o] = 0.f;
        const float* wp = w2 + h * (FN*HID);
#pragma unroll
        for (int i = 0; i < FN; ++i) {
            float xi = xv[i];
#pragma unroll
            for (int o = 0; o < HID; ++o)
                t[o] = fmaf(xi, wp[i*HID + o], t[o]);
        }
        float uh = u[h];
#pragma unroll
        for (int o = 0; o < HID; ++o) msg[o] = fmaf(uh, t[o], msg[o]);
    }
    float* ap = agg + (size_t)dst * HID;
#pragma unroll
    for (int o = 0; o < HID; ++o) atomicAdd(ap + o, msg[o]);
}

__global__ __launch_bounds__(256) void node0_k(
    const float* __restrict__ x, const float* __restrict__ agg,
    const float* __restrict__ root, const float* __restrict__ bias,
    float* __restrict__ h)
{
    int idx = blockIdx.x * 256 + threadIdx.x;
    if (idx >= N_NODES * HID) return;
    int n = idx >> 4;
    int o = idx & 15;
    float s = agg[idx] + bias[o];
    const float* xr = x + (size_t)n * FN;
#pragma unroll
    for (int i = 0; i < FN; ++i) s = fmaf(xr[i], root[i*HID + o], s);
    h[idx] = fmaxf(s, 0.f);
}

__global__ __launch_bounds__(256) void conv1_edge_k(
    const float* __restrict__ hin, const float* __restrict__ ea,
    const int* __restrict__ ei,
    const float* __restrict__ w1, const float* __restrict__ b1,
    const float* __restrict__ w2, const float* __restrict__ b2,
    float* __restrict__ agg)
{
    int e = blockIdx.x * 256 + threadIdx.x;
    if (e >= E_EDGES) return;
    int src = ei[e];
    int dst = ei[E_EDGES + e];
    float eav[FE];
    load8(ea + (size_t)e * FE, eav);
    float u[IH];
    edge_mlp_seq(eav, w1, b1, u);
    float hv[HID];
    load8(hin + (size_t)src * HID,     hv);
    load8(hin + (size_t)src * HID + 8, hv + 8);
    float msg[IH];
#pragma unroll
    for (int o = 0; o < IH; ++o) msg[o] = 0.f;
#pragma unroll
    for (int i = 0; i < HID; ++i) {
        float hi = hv[i];
#pragma unroll
        for (int o = 0; o < IH; ++o)
            msg[o] = fmaf(hi, b2[i*IH + o], msg[o]);
    }
#pragma unroll
    for (int hh = 0; hh < IH; ++hh) {
        float t[IH];
#pragma unroll
        for (int o = 0; o < IH; ++o) t[o] = 0.f;
        const float* wp = w2 + hh * (HID*IH);
#pragma unroll
        for (int i = 0; i < HID; ++i) {
            float hi = hv[i];
#pragma unroll
            for (int o = 0; o < IH; ++o)
                t[o] = fmaf(hi, wp[i*IH + o], t[o]);
        }
        float uh = u[hh];
#pragma unroll
        for (int o = 0; o < IH; ++o) msg[o] = fmaf(uh, t[o], msg[o]);
    }
    float* ap = agg + (size_t)dst * IH;
#pragma unroll
    for (int o = 0; o < IH; ++o) atomicAdd(ap + o, msg[o]);
}

__global__ __launch_bounds__(256) void node1_k(
    const float* __restrict__ hin, const float* __restrict__ agg,
    const float* __restrict__ root, const float* __restrict__ bias,
    float* __restrict__ h2)
{
    int idx = blockIdx.x * 256 + threadIdx.x;
    if (idx >= N_NODES * IH) return;
    int n = idx / IH;
    int o = idx - n * IH;
    float s = agg[idx] + bias[o];
    const float* hr = hin + (size_t)n * HID;
#pragma unroll
    for (int i = 0; i < HID; ++i) s = fmaf(hr[i], root[i*IH + o], s);
    h2[idx] = fmaxf(s, 0.f);
}

extern "C" void kernel_launch(void* const* d_in, const int* in_sizes, int n_in,
                              void* d_out, int out_size, void* d_ws, size_t ws_size,
                              hipStream_t stream) {
    const float* x       = (const float*)d_in[0];
    const float* ea      = (const float*)d_in[1];
    const int*   ei      = (const int*)  d_in[2];
    const float* c0_w1   = (const float*)d_in[3];
    const float* c0_b1   = (const float*)d_in[4];
    const float* c0_w2   = (const float*)d_in[5];
    const float* c0_b2   = (const float*)d_in[6];
    const float* c0_root = (const float*)d_in[7];
    const float* c0_bias = (const float*)d_in[8];
    const float* c1_w1   = (const float*)d_in[9];
    const float* c1_b1   = (const float*)d_in[10];
    const float* c1_w2   = (const float*)d_in[11];
    const float* c1_b2   = (const float*)d_in[12];
    const float* c1_root = (const float*)d_in[13];
    const float* c1_bias = (const float*)d_in[14];
    const float* ep_w1   = (const float*)d_in[15];
    const float* ep_b1   = (const float*)d_in[16];
    const float* ep_w2   = (const float*)d_in[17];
    const float* ep_b2   = (const float*)d_in[18];
    float* out = (float*)d_out;

    int eb = (E_EDGES + 255) / 256;

    if (ws_size >= WS_NEED) {
        int*   wi     = (int*)d_ws;
        int*   offset = wi + I_OFF;
        int*   rank   = wi + I_RANK;
        int*   bsum   = wi + I_BSUM;
        int*   bbase  = wi + I_BBASE;
        float* wf     = (float*)(wi + I_TOTAL);
        float* h      = wf + F_H;
        float* h2     = wf + F_H2;
        // padded counters alias the msg region (dead before conv0 writes msgs)
        int*            cntP  = (int*)(wf + F_MSG);
        unsigned*       msgu  = (unsigned*)(wf + F_MSG);
        unsigned short* msg16 = (unsigned short*)(wf + F_MSG);

        hipMemsetAsync(cntP, 0, (size_t)N_NODES * 16 * sizeof(int), stream);
        count_rank_k<<<eb, 256, 0, stream>>>(ei, cntP, rank);
        blocksum_k<<<NB_SCAN, 256, 0, stream>>>(cntP, bsum);
        scan_bsums_k<<<1, 256, 0, stream>>>(bsum, bbase);
        offsets_k<<<NB_SCAN, 256, 0, stream>>>(cntP, bbase, offset);

        conv0_scatter_k<<<eb, 256, 0, stream>>>(x, ea, ei, c0_w1, c0_b1, c0_w2, c0_b2,
                                                offset, rank, msgu);
        node0_red_k<<<(N_NODES*HID + 255)/256, 256, 0, stream>>>(x, msg16, offset,
                                                                 c0_root, c0_bias, h);
        conv1_scatter_k<<<eb, 256, 0, stream>>>(h, ea, ei, c1_w1, c1_b1, c1_w2, c1_b2,
                                                offset, rank, msgu);
        node1_red_k<<<(N_NODES*IH + 255)/256, 256, 0, stream>>>(h, msg16, offset,
                                                                c1_root, c1_bias, h2);
        edge_pred_k<<<eb, 256, 0, stream>>>(h2, ea, ei, ep_w1, ep_b1, ep_w2, ep_b2, out);
    } else {
        float* ws   = (float*)d_ws;
        float* agg0 = ws;
        float* agg1 = ws + 800000;
        float* h    = ws + 1300000;
        float* h2   = ws + 2100000;
        hipMemsetAsync(d_ws, 0, 1300000 * sizeof(float), stream);
        conv0_edge_k<<<eb, 256, 0, stream>>>(x, ea, ei, c0_w1, c0_b1, c0_w2, c0_b2, agg0);
        node0_k<<<(N_NODES*HID + 255)/256, 256, 0, stream>>>(x, agg0, c0_root, c0_bias, h);
        conv1_edge_k<<<eb, 256, 0, stream>>>(h, ea, ei, c1_w1, c1_b1, c1_w2, c1_b2, agg1);
        node1_k<<<(N_NODES*IH + 255)/256, 256, 0, stream>>>(h, agg1, c1_root, c1_bias, h2);
        edge_pred_k<<<eb, 256, 0, stream>>>(h2, ea, ei, ep_w1, ep_b1, ep_w2, ep_b2, out);
    }
}

// Round 15
// 273.910 us; speedup vs baseline: 1.2613x; 1.2613x over previous
//
#include <hip/hip_runtime.h>

#define N_NODES 50000
#define E_EDGES 1600000
#define FN 8
#define FE 8
#define HID 16
#define IH 10
#define NB_SCAN 196   // ceil(50000/256)

// ---------------- workspace layout ----------------
#define I_OFF   50048
#define I_RANK  100096
#define I_BSUM  1700096
#define I_BBASE 1700352
#define I_TOTAL 1700608
#define F_H     0
#define F_H2    800000
#define F_MSG   1300000
#define F_TOTAL 26900000
#define WS_NEED ((size_t)I_TOTAL*4 + (size_t)F_TOTAL*4)

// ================= CSR build (padded counters: one per 64B line) =================
__global__ __launch_bounds__(256) void count_rank_k(
    const int* __restrict__ ei, int* __restrict__ cntP, int* __restrict__ rank)
{
    int e = blockIdx.x * 256 + threadIdx.x;
    if (e >= E_EDGES) return;
    int dst = ei[E_EDGES + e];
    rank[e] = atomicAdd(&cntP[dst * 16], 1);
}

__global__ __launch_bounds__(256) void blocksum_k(
    const int* __restrict__ cntP, int* __restrict__ bsum)
{
    __shared__ int sh[256];
    int t = threadIdx.x;
    int idx = blockIdx.x * 256 + t;
    sh[t] = (idx < N_NODES) ? cntP[idx * 16] : 0;
    __syncthreads();
#pragma unroll
    for (int d = 128; d > 0; d >>= 1) {
        if (t < d) sh[t] += sh[t + d];
        __syncthreads();
    }
    if (t == 0) bsum[blockIdx.x] = sh[0];
}

__global__ __launch_bounds__(256) void scan_bsums_k(
    const int* __restrict__ bsum, int* __restrict__ bbase)
{
    __shared__ int sh[256];
    int t = threadIdx.x;
    int v = (t < NB_SCAN) ? bsum[t] : 0;
    sh[t] = v;
    __syncthreads();
#pragma unroll
    for (int d = 1; d < 256; d <<= 1) {
        int u = (t >= d) ? sh[t - d] : 0;
        __syncthreads();
        sh[t] += u;
        __syncthreads();
    }
    if (t < NB_SCAN) bbase[t] = sh[t] - v;
}

__global__ __launch_bounds__(256) void offsets_k(
    const int* __restrict__ cntP, const int* __restrict__ bbase,
    int* __restrict__ offset)
{
    __shared__ int sh[256];
    int t = threadIdx.x;
    int b = blockIdx.x;
    int idx = b * 256 + t;
    int v = (idx < N_NODES) ? cntP[idx * 16] : 0;
    sh[t] = v;
    __syncthreads();
#pragma unroll
    for (int d = 1; d < 256; d <<= 1) {
        int u = (t >= d) ? sh[t - d] : 0;
        __syncthreads();
        sh[t] += u;
        __syncthreads();
    }
    int incl = sh[t];
    int base = bbase[b];
    if (idx < N_NODES) offset[idx] = base + incl - v;
    if (idx == N_NODES - 1) offset[N_NODES] = base + incl;
}

// ================= helpers =================
__device__ __forceinline__ void load8(const float* __restrict__ p, float v[8]) {
    const float4* q = reinterpret_cast<const float4*>(p);
    float4 a = q[0], b = q[1];
    v[0]=a.x; v[1]=a.y; v[2]=a.z; v[3]=a.w;
    v[4]=b.x; v[5]=b.y; v[6]=b.z; v[7]=b.w;
}

__device__ __forceinline__ void edge_mlp_seq(
    const float eav[FE], const float* __restrict__ w1,
    const float* __restrict__ b1, float u[IH])
{
#pragma unroll
    for (int h = 0; h < IH; ++h) u[h] = b1[h];
#pragma unroll
    for (int k = 0; k < FE; ++k) {
        float ek = eav[k];
#pragma unroll
        for (int h = 0; h < IH; ++h) u[h] = fmaf(ek, w1[k*IH + h], u[h]);
    }
#pragma unroll
    for (int h = 0; h < IH; ++h) u[h] = fmaxf(u[h], 0.f);
}

// round-to-nearest bf16x2 pack (bit trick, ~5 VALU)
__device__ __forceinline__ unsigned pk2(float a, float b) {
    unsigned au = __float_as_uint(a) + 0x8000u;
    unsigned bu = __float_as_uint(b) + 0x8000u;
    return (au >> 16) | (bu & 0xFFFF0000u);
}
__device__ __forceinline__ float upbf(unsigned short us) {
    return __uint_as_float(((unsigned)us) << 16);
}

// ================= conv0: 1 edge/thread, LDS transpose + bf16 coalesced scatter =
// bf16 rows: 16 x 2B = 32B; lane PAIRS write one row (2 x 16B).
__global__ __launch_bounds__(256) void conv0_scatter_k(
    const float* __restrict__ x, const float* __restrict__ ea,
    const int* __restrict__ ei,
    const float* __restrict__ w1, const float* __restrict__ b1,
    const float* __restrict__ w2, const float* __restrict__ b2,
    const int* __restrict__ offset, const int* __restrict__ rank,
    unsigned* __restrict__ msgu)         // bf16 msgbuf viewed as u32; row = pos*8
{
    __shared__ float smsg[256 * 17];
    __shared__ int   plds[256];

    int t = threadIdx.x;
    int e = blockIdx.x * 256 + t;        // grid exact: E/256
    int src = ei[e];
    int dst = ei[E_EDGES + e];
    plds[t] = offset[dst] + rank[e];

    float eav[FE];
    load8(ea + (size_t)e * FE, eav);
    float u[IH];
    edge_mlp_seq(eav, w1, b1, u);
    float xv[FN];
    load8(x + (size_t)src * FN, xv);

    float msg[HID];
#pragma unroll
    for (int o = 0; o < HID; ++o) msg[o] = 0.f;
#pragma unroll
    for (int i = 0; i < FN; ++i) {
        float xi = xv[i];
#pragma unroll
        for (int o = 0; o < HID; ++o)
            msg[o] = fmaf(xi, b2[i*HID + o], msg[o]);
    }
#pragma unroll
    for (int h = 0; h < IH; ++h) {
        float tt[HID];
#pragma unroll
        for (int o = 0; o < HID; ++o) tt[o] = 0.f;
        const float* wp = w2 + h * (FN*HID);
#pragma unroll
        for (int i = 0; i < FN; ++i) {
            float xi = xv[i];
#pragma unroll
            for (int o = 0; o < HID; ++o)
                tt[o] = fmaf(xi, wp[i*HID + o], tt[o]);
        }
        float uh = u[h];
#pragma unroll
        for (int o = 0; o < HID; ++o) msg[o] = fmaf(uh, tt[o], msg[o]);
    }

#pragma unroll
    for (int o = 0; o < HID; ++o) smsg[t*17 + o] = msg[o];
    __syncthreads();

    int q   = t & 1;        // 16B half of the 32B row
    int eb0 = t >> 1;       // 0..127
#pragma unroll
    for (int rep = 0; rep < 2; ++rep) {
        int eL  = eb0 + rep * 128;
        int pos = plds[eL];
        const float* s = &smsg[eL*17 + q*8];
        uint4 v;
        v.x = pk2(s[0], s[1]); v.y = pk2(s[2], s[3]);
        v.z = pk2(s[4], s[5]); v.w = pk2(s[6], s[7]);
        *reinterpret_cast<uint4*>(msgu + (size_t)pos * 8 + q * 4) = v;
    }
}

// ================= node0: bf16 segmented reduce + root + relu =================
__global__ __launch_bounds__(256) void node0_red_k(
    const float* __restrict__ x, const unsigned short* __restrict__ msg16,
    const int* __restrict__ offset,
    const float* __restrict__ root, const float* __restrict__ bias,
    float* __restrict__ h)
{
    int idx = blockIdx.x * 256 + threadIdx.x;
    if (idx >= N_NODES * HID) return;
    int n = idx >> 4;
    int o = idx & 15;
    int beg = offset[n], end = offset[n + 1];
    float s = bias[o];
    for (int j = beg; j < end; ++j) s += upbf(msg16[(size_t)j * 16 + o]);
    const float* xr = x + (size_t)n * FN;
#pragma unroll
    for (int i = 0; i < FN; ++i) s = fmaf(xr[i], root[i*HID + o], s);
    h[idx] = fmaxf(s, 0.f);
}

// ================= conv1: 1 edge/thread, LDS transpose + bf16 coalesced scatter =
__global__ __launch_bounds__(256) void conv1_scatter_k(
    const float* __restrict__ hin, const float* __restrict__ ea,
    const int* __restrict__ ei,
    const float* __restrict__ w1, const float* __restrict__ b1,
    const float* __restrict__ w2, const float* __restrict__ b2,
    const int* __restrict__ offset, const int* __restrict__ rank,
    unsigned* __restrict__ msgu)         // bf16 rows, 16 slots (10 used)
{
    __shared__ float smsg[256 * 17];
    __shared__ int   plds[256];

    int t = threadIdx.x;
    int e = blockIdx.x * 256 + t;
    int src = ei[e];
    int dst = ei[E_EDGES + e];
    plds[t] = offset[dst] + rank[e];

    float eav[FE];
    load8(ea + (size_t)e * FE, eav);
    float u[IH];
    edge_mlp_seq(eav, w1, b1, u);
    float hv[HID];
    load8(hin + (size_t)src * HID,     hv);
    load8(hin + (size_t)src * HID + 8, hv + 8);

    float msg[HID];
#pragma unroll
    for (int o = 0; o < HID; ++o) msg[o] = 0.f;
#pragma unroll
    for (int i = 0; i < HID; ++i) {
        float hi = hv[i];
#pragma unroll
        for (int o = 0; o < IH; ++o)
            msg[o] = fmaf(hi, b2[i*IH + o], msg[o]);
    }
#pragma unroll
    for (int hh = 0; hh < IH; ++hh) {
        float tt[IH];
#pragma unroll
        for (int o = 0; o < IH; ++o) tt[o] = 0.f;
        const float* wp = w2 + hh * (HID*IH);
#pragma unroll
        for (int i = 0; i < HID; ++i) {
            float hi = hv[i];
#pragma unroll
            for (int o = 0; o < IH; ++o)
                tt[o] = fmaf(hi, wp[i*IH + o], tt[o]);
        }
        float uh = u[hh];
#pragma unroll
        for (int o = 0; o < IH; ++o) msg[o] = fmaf(uh, tt[o], msg[o]);
    }

#pragma unroll
    for (int o = 0; o < HID; ++o) smsg[t*17 + o] = msg[o];   // 10..15 zeros
    __syncthreads();

    int q   = t & 1;
    int eb0 = t >> 1;
#pragma unroll
    for (int rep = 0; rep < 2; ++rep) {
        int eL  = eb0 + rep * 128;
        int pos = plds[eL];
        const float* s = &smsg[eL*17 + q*8];
        uint4 v;
        v.x = pk2(s[0], s[1]); v.y = pk2(s[2], s[3]);
        v.z = pk2(s[4], s[5]); v.w = pk2(s[6], s[7]);
        *reinterpret_cast<uint4*>(msgu + (size_t)pos * 8 + q * 4) = v;
    }
}

// ================= node1: bf16 segmented reduce + root + relu =================
__global__ __launch_bounds__(256) void node1_red_k(
    const float* __restrict__ hin, const unsigned short* __restrict__ msg16,
    const int* __restrict__ offset,
    const float* __restrict__ root, const float* __restrict__ bias,
    float* __restrict__ h2)
{
    int idx = blockIdx.x * 256 + threadIdx.x;
    if (idx >= N_NODES * IH) return;
    int n = idx / IH;
    int o = idx - n * IH;
    int beg = offset[n], end = offset[n + 1];
    float s = bias[o];
    for (int j = beg; j < end; ++j) s += upbf(msg16[(size_t)j * 16 + o]);
    const float* hr = hin + (size_t)n * HID;
#pragma unroll
    for (int i = 0; i < HID; ++i) s = fmaf(hr[i], root[i*IH + o], s);
    h2[idx] = fmaxf(s, 0.f);
}

// ================= edge predictor =================
__global__ __launch_bounds__(256) void edge_pred_k(
    const float* __restrict__ h2, const float* __restrict__ ea,
    const int* __restrict__ ei,
    const float* __restrict__ w1, const float* __restrict__ b1,
    const float* __restrict__ w2, const float* __restrict__ b2,
    float* __restrict__ out)
{
    int e = blockIdx.x * 256 + threadIdx.x;
    if (e >= E_EDGES) return;
    int src = ei[e];
    float eav[FE];
    load8(ea + (size_t)e * FE, eav);
    float hv[IH];
    {
        const float2* p = reinterpret_cast<const float2*>(h2 + (size_t)src * IH);
        float2 a = p[0], b = p[1], c = p[2], d = p[3], f = p[4];
        hv[0]=a.x; hv[1]=a.y; hv[2]=b.x; hv[3]=b.y; hv[4]=c.x;
        hv[5]=c.y; hv[6]=d.x; hv[7]=d.y; hv[8]=f.x; hv[9]=f.y;
    }
    float t[IH];
#pragma unroll
    for (int j = 0; j < IH; ++j) t[j] = b1[j];
#pragma unroll
    for (int k = 0; k < FE; ++k) {
        float ek = eav[k];
#pragma unroll
        for (int j = 0; j < IH; ++j) t[j] = fmaf(ek, w1[k*IH + j], t[j]);
    }
#pragma unroll
    for (int k = 0; k < IH; ++k) {
        float hk = hv[k];
#pragma unroll
        for (int j = 0; j < IH; ++j) t[j] = fmaf(hk, w1[(FE + k)*IH + j], t[j]);
    }
    float score = b2[0];
#pragma unroll
    for (int j = 0; j < IH; ++j)
        score = fmaf(fmaxf(t[j], 0.f), w2[j], score);
    out[e] = score;
}

// ================= fallback (atomic) path =================
__global__ __launch_bounds__(256) void conv0_edge_k(
    const float* __restrict__ x, const float* __restrict__ ea,
    const int* __restrict__ ei,
    const float* __restrict__ w1, const float* __restrict__ b1,
    const float* __restrict__ w2, const float* __restrict__ b2,
    float* __restrict__ agg)
{
    int e = blockIdx.x * 256 + threadIdx.x;
    if (e >= E_EDGES) return;
    int src = ei[e];
    int dst = ei[E_EDGES + e];
    float eav[FE];
    load8(ea + (size_t)e * FE, eav);
    float u[IH];
    edge_mlp_seq(eav, w1, b1, u);
    float xv[FN];
    load8(x + (size_t)src * FN, xv);
    float msg[HID];
#pragma unroll
    for (int o = 0; o < HID; ++o) msg[o] = 0.f;
#pragma unroll
    for (int i = 0; i < FN; ++i) {
        float xi = xv[i];
#pragma unroll
        for (int o = 0; o < HID; ++o)
            msg[o] = fmaf(xi, b2[i*HID + o], msg[o]);
    }
#pragma unroll
    for (int h = 0; h < IH; ++h) {
        float t[HID];
#pragma unroll
        for (int o = 0; o < HID; ++o) t[o] = 0.f;
        const float* wp = w2 + h * (FN*HID);
#pragma unroll
        for (int i = 0; i < FN; ++i) {
            float xi = xv[i];
#pragma unroll
            for (int o = 0; o < HID; ++o)
                t[o] = fmaf(xi, wp[i*HID + o], t[o]);
        }
        float uh = u[h];
#pragma unroll
        for (int o = 0; o < HID; ++o) msg[o] = fmaf(uh, t[o], msg[o]);
    }
    float* ap = agg + (size_t)dst * HID;
#pragma unroll
    for (int o = 0; o < HID; ++o) atomicAdd(ap + o, msg[o]);
}

__global__ __launch_bounds__(256) void node0_k(
    const float* __restrict__ x, const float* __restrict__ agg,
    const float* __restrict__ root, const float* __restrict__ bias,
    float* __restrict__ h)
{
    int idx = blockIdx.x * 256 + threadIdx.x;
    if (idx >= N_NODES * HID) return;
    int n = idx >> 4;
    int o = idx & 15;
    float s = agg[idx] + bias[o];
    const float* xr = x + (size_t)n * FN;
#pragma unroll
    for (int i = 0; i < FN; ++i) s = fmaf(xr[i], root[i*HID + o], s);
    h[idx] = fmaxf(s, 0.f);
}

__global__ __launch_bounds__(256) void conv1_edge_k(
    const float* __restrict__ hin, const float* __restrict__ ea,
    const int* __restrict__ ei,
    const float* __restrict__ w1, const float* __restrict__ b1,
    const float* __restrict__ w2, const float* __restrict__ b2,
    float* __restrict__ agg)
{
    int e = blockIdx.x * 256 + threadIdx.x;
    if (e >= E_EDGES) return;
    int src = ei[e];
    int dst = ei[E_EDGES + e];
    float eav[FE];
    load8(ea + (size_t)e * FE, eav);
    float u[IH];
    edge_mlp_seq(eav, w1, b1, u);
    float hv[HID];
    load8(hin + (size_t)src * HID,     hv);
    load8(hin + (size_t)src * HID + 8, hv + 8);
    float msg[IH];
#pragma unroll
    for (int o = 0; o < IH; ++o) msg[o] = 0.f;
#pragma unroll
    for (int i = 0; i < HID; ++i) {
        float hi = hv[i];
#pragma unroll
        for (int o = 0; o < IH; ++o)
            msg[o] = fmaf(hi, b2[i*IH + o], msg[o]);
    }
#pragma unroll
    for (int hh = 0; hh < IH; ++hh) {
        float t[IH];
#pragma unroll
        for (int o = 0; o < IH; ++o) t[o] = 0.f;
        const float* wp = w2 + hh * (HID*IH);
#pragma unroll
        for (int i = 0; i < HID; ++i) {
            float hi = hv[i];
#pragma unroll
            for (int o = 0; o < IH; ++o)
                t[o] = fmaf(hi, wp[i*IH + o], t[o]);
        }
        float uh = u[hh];
#pragma unroll
        for (int o = 0; o < IH; ++o) msg[o] = fmaf(uh, t[o], msg[o]);
    }
    float* ap = agg + (size_t)dst * IH;
#pragma unroll
    for (int o = 0; o < IH; ++o) atomicAdd(ap + o, msg[o]);
}

__global__ __launch_bounds__(256) void node1_k(
    const float* __restrict__ hin, const float* __restrict__ agg,
    const float* __restrict__ root, const float* __restrict__ bias,
    float* __restrict__ h2)
{
    int idx = blockIdx.x * 256 + threadIdx.x;
    if (idx >= N_NODES * IH) return;
    int n = idx / IH;
    int o = idx - n * IH;
    float s = agg[idx] + bias[o];
    const float* hr = hin + (size_t)n * HID;
#pragma unroll
    for (int i = 0; i < HID; ++i) s = fmaf(hr[i], root[i*IH + o], s);
    h2[idx] = fmaxf(s, 0.f);
}

extern "C" void kernel_launch(void* const* d_in, const int* in_sizes, int n_in,
                              void* d_out, int out_size, void* d_ws, size_t ws_size,
                              hipStream_t stream) {
    const float* x       = (const float*)d_in[0];
    const float* ea      = (const float*)d_in[1];
    const int*   ei      = (const int*)  d_in[2];
    const float* c0_w1   = (const float*)d_in[3];
    const float* c0_b1   = (const float*)d_in[4];
    const float* c0_w2   = (const float*)d_in[5];
    const float* c0_b2   = (const float*)d_in[6];
    const float* c0_root = (const float*)d_in[7];
    const float* c0_bias = (const float*)d_in[8];
    const float* c1_w1   = (const float*)d_in[9];
    const float* c1_b1   = (const float*)d_in[10];
    const float* c1_w2   = (const float*)d_in[11];
    const float* c1_b2   = (const float*)d_in[12];
    const float* c1_root = (const float*)d_in[13];
    const float* c1_bias = (const float*)d_in[14];
    const float* ep_w1   = (const float*)d_in[15];
    const float* ep_b1   = (const float*)d_in[16];
    const float* ep_w2   = (const float*)d_in[17];
    const float* ep_b2   = (const float*)d_in[18];
    float* out = (float*)d_out;

    int eb = (E_EDGES + 255) / 256;

    if (ws_size >= WS_NEED) {
        int*   wi     = (int*)d_ws;
        int*   offset = wi + I_OFF;
        int*   rank   = wi + I_RANK;
        int*   bsum   = wi + I_BSUM;
        int*   bbase  = wi + I_BBASE;
        float* wf     = (float*)(wi + I_TOTAL);
        float* h      = wf + F_H;
        float* h2     = wf + F_H2;
        // padded counters alias the msg region (dead before conv0 writes msgs)
        int*            cntP  = (int*)(wf + F_MSG);
        unsigned*       msgu  = (unsigned*)(wf + F_MSG);
        unsigned short* msg16 = (unsigned short*)(wf + F_MSG);

        hipMemsetAsync(cntP, 0, (size_t)N_NODES * 16 * sizeof(int), stream);
        count_rank_k<<<eb, 256, 0, stream>>>(ei, cntP, rank);
        blocksum_k<<<NB_SCAN, 256, 0, stream>>>(cntP, bsum);
        scan_bsums_k<<<1, 256, 0, stream>>>(bsum, bbase);
        offsets_k<<<NB_SCAN, 256, 0, stream>>>(cntP, bbase, offset);

        conv0_scatter_k<<<eb, 256, 0, stream>>>(x, ea, ei, c0_w1, c0_b1, c0_w2, c0_b2,
                                                offset, rank, msgu);
        node0_red_k<<<(N_NODES*HID + 255)/256, 256, 0, stream>>>(x, msg16, offset,
                                                                 c0_root, c0_bias, h);
        conv1_scatter_k<<<eb, 256, 0, stream>>>(h, ea, ei, c1_w1, c1_b1, c1_w2, c1_b2,
                                                offset, rank, msgu);
        node1_red_k<<<(N_NODES*IH + 255)/256, 256, 0, stream>>>(h, msg16, offset,
                                                                c1_root, c1_bias, h2);
        edge_pred_k<<<eb, 256, 0, stream>>>(h2, ea, ei, ep_w1, ep_b1, ep_w2, ep_b2, out);
    } else {
        float* ws   = (float*)d_ws;
        float* agg0 = ws;
        float* agg1 = ws + 800000;
        float* h    = ws + 1300000;
        float* h2   = ws + 2100000;
        hipMemsetAsync(d_ws, 0, 1300000 * sizeof(float), stream);
        conv0_edge_k<<<eb, 256, 0, stream>>>(x, ea, ei, c0_w1, c0_b1, c0_w2, c0_b2, agg0);
        node0_k<<<(N_NODES*HID + 255)/256, 256, 0, stream>>>(x, agg0, c0_root, c0_bias, h);
        conv1_edge_k<<<eb, 256, 0, stream>>>(h, ea, ei, c1_w1, c1_b1, c1_w2, c1_b2, agg1);
        node1_k<<<(N_NODES*IH + 255)/256, 256, 0, stream>>>(h, agg1, c1_root, c1_bias, h2);
        edge_pred_k<<<eb, 256, 0, stream>>>(h2, ea, ei, ep_w1, ep_b1, ep_w2, ep_b2, out);
    }
}